// Round 2
// baseline (187.203 us; speedup 1.0000x reference)
//
#include <hip/hip_runtime.h>

#define HH 1024
#define WW 1024

typedef float v2 __attribute__((ext_vector_type(2)));

// Thread: column pair (x0 even, x0+1) x 4 consecutive rows -> 4 computed +
// 4 pass-through pixels. Accumulators packed over channel pairs so the conv
// core is v_pk_fma_f32 (2 MACs/issue). Filters staged in LDS [tap][16ch],
// read per tap as 4x b128 broadcast (conflict-free), amortized over 4 pixels.
__global__ __launch_bounds__(256, 1)
void demosaick_kernel(const float* __restrict__ mosaick,
                      const float* __restrict__ sel_filts,
                      const float* __restrict__ green_filts,
                      float* __restrict__ out) {
    __shared__ float filt[25][16];  // [tap][0..7]=sel, [8..15]=green

    const int tid = threadIdx.y * 64 + threadIdx.x;
    for (int idx = tid; idx < 400; idx += 256) {
        int half = idx / 200;            // 0 = sel, 1 = green
        int j = idx - half * 200;        // j = k*25 + tap
        int k = j / 25;
        int t = j - k * 25;
        filt[t][half * 8 + k] = half ? green_filts[j] : sel_filts[j];
    }
    __syncthreads();

    const int b  = blockIdx.z;
    const int y0 = blockIdx.y * 16 + threadIdx.y * 4;       // even
    const int x0 = (blockIdx.x * 64 + threadIdx.x) * 2;     // even
    const float* img = mosaick + (size_t)b * (HH * WW);

    // 8 rows x 6 cols window: rows y0-2..y0+5, cols x0-2..x0+3.
    float win[8][6];
    const bool interior = (blockIdx.x != 0) & (blockIdx.x != gridDim.x - 1) &
                          (blockIdx.y != 0) & (blockIdx.y != gridDim.y - 1);
    if (interior) {
        // No clamping needed; x0-2 is even -> 8B-aligned float2 loads.
        #pragma unroll
        for (int j = 0; j < 8; ++j) {
            const float2* rp = (const float2*)(img + (size_t)(y0 + j - 2) * WW + (x0 - 2));
            float2 a = rp[0], c = rp[1], e = rp[2];
            win[j][0] = a.x; win[j][1] = a.y;
            win[j][2] = c.x; win[j][3] = c.y;
            win[j][4] = e.x; win[j][5] = e.y;
        }
    } else {
        #pragma unroll
        for (int j = 0; j < 8; ++j) {
            int r = y0 + j - 2;
            r = r < 0 ? 0 : (r > HH - 1 ? HH - 1 : r);
            const float* rp = img + (size_t)r * WW;
            #pragma unroll
            for (int i = 0; i < 6; ++i) {
                int c = x0 + i - 2;
                c = c < 0 ? 0 : (c > WW - 1 ? WW - 1 : c);
                win[j][i] = rp[c];
            }
        }
    }

    v2 accS[4][4];   // [pixel][channel-pair] selection scores
    v2 accG[4][4];   // green candidates
    #pragma unroll
    for (int p = 0; p < 4; ++p)
        #pragma unroll
        for (int q = 0; q < 4; ++q) { accS[p][q] = (v2)(0.f); accG[p][q] = (v2)(0.f); }

    const float4* fl4 = (const float4*)&filt[0][0];
    #pragma unroll
    for (int dy = 0; dy < 5; ++dy) {
        #pragma unroll
        for (int dx = 0; dx < 5; ++dx) {
            const int t = dy * 5 + dx;
            float4 s0 = fl4[t * 4 + 0], s1 = fl4[t * 4 + 1];
            float4 g0 = fl4[t * 4 + 2], g1 = fl4[t * 4 + 3];
            v2 fS[4], fG[4];
            fS[0].x = s0.x; fS[0].y = s0.y; fS[1].x = s0.z; fS[1].y = s0.w;
            fS[2].x = s1.x; fS[2].y = s1.y; fS[3].x = s1.z; fS[3].y = s1.w;
            fG[0].x = g0.x; fG[0].y = g0.y; fG[1].x = g0.z; fG[1].y = g0.w;
            fG[2].x = g1.x; fG[2].y = g1.y; fG[3].x = g1.z; fG[3].y = g1.w;
            #pragma unroll
            for (int p = 0; p < 4; ++p) {
                // p even -> row even -> computed pixel at x0+1 (window col dx+1)
                // p odd  -> row odd  -> computed pixel at x0   (window col dx)
                float v = win[p + dy][dx + ((p & 1) ^ 1)];
                v2 vv; vv.x = v; vv.y = v;
                #pragma unroll
                for (int q = 0; q < 4; ++q) {
                    accS[p][q] = __builtin_elementwise_fma(vv, fS[q], accS[p][q]);
                    accG[p][q] = __builtin_elementwise_fma(vv, fG[q], accG[p][q]);
                }
            }
        }
    }

    float* outp = out + (size_t)b * (HH * WW);
    #pragma unroll
    for (int p = 0; p < 4; ++p) {
        float sc[8], gc[8];
        #pragma unroll
        for (int q = 0; q < 4; ++q) {
            sc[2 * q] = accS[p][q].x; sc[2 * q + 1] = accS[p][q].y;
            gc[2 * q] = accG[p][q].x; gc[2 * q + 1] = accG[p][q].y;
        }
        float m = sc[0];
        #pragma unroll
        for (int k = 1; k < 8; ++k) m = fmaxf(m, sc[k]);
        float s = 0.f, gh = 0.f;
        #pragma unroll
        for (int k = 0; k < 8; ++k) {
            float e = __expf(sc[k] - m);
            s += e;
            gh = fmaf(e, gc[k], gh);
        }
        gh *= __builtin_amdgcn_rcpf(s);
        float2 o;
        if ((p & 1) == 0) { o.x = win[p + 2][2]; o.y = gh; }            // green at x0
        else              { o.x = gh;            o.y = win[p + 2][3]; } // green at x0+1
        *(float2*)(outp + (size_t)(y0 + p) * WW + x0) = o;
    }
}

extern "C" void kernel_launch(void* const* d_in, const int* in_sizes, int n_in,
                              void* d_out, int out_size, void* d_ws, size_t ws_size,
                              hipStream_t stream) {
    const float* mosaick     = (const float*)d_in[0];
    const float* sel_filts   = (const float*)d_in[1];
    const float* green_filts = (const float*)d_in[2];
    float* out = (float*)d_out;
    const int HW = HH * WW;
    const int B = in_sizes[0] / HW;          // 8
    dim3 grid(WW / 128, HH / 16, B);         // (8, 64, 8) = 4096 blocks
    dim3 block(64, 4, 1);
    hipLaunchKernelGGL(demosaick_kernel, grid, block, 0, stream,
                       mosaick, sel_filts, green_filts, out);
}

// Round 4
// 119.247 us; speedup vs baseline: 1.5699x; 1.5699x over previous
//
#include <hip/hip_runtime.h>

#define HH 1024
#define WW 1024

typedef __fp16 h2 __attribute__((ext_vector_type(2)));

// Thread: column pair (x0 even, x0+1) x 4 consecutive rows -> 4 computed +
// 4 pass-through pixels. Conv core is v_dot2_f32_f16 (fp16 pairs over the
// dx dimension, fp32 accumulate): taps pair as (0,1),(2,3),(4,pad).
// Even rows (computed pixel at x0+1, window offset 1) use odd-aligned window
// pairs; odd rows use even-aligned pairs. Both alignments packed once per
// window row and shared across the 4 pixels.
// Filters staged in LDS as half2 [dy*3+pair][16ch] (sel ch0-7, green ch8-15),
// read broadcast (uniform address). Green bank processed in two 4-channel
// passes to keep peak VGPRs < 128 (launch_bounds (256,2): R2 showed that
// letting the allocator past 128 causes scratch spills + occupancy collapse).
__global__ __launch_bounds__(256, 2)
void demosaick_kernel(const float* __restrict__ mosaick,
                      const float* __restrict__ sel_filts,
                      const float* __restrict__ green_filts,
                      float* __restrict__ out) {
    __shared__ h2 filt2[15 * 16];  // [dy*3+pair][ch]; 960 B

    const int tid = threadIdx.y * 64 + threadIdx.x;
    if (tid < 240) {
        int ch = tid & 15;
        int t  = tid >> 4;          // 0..14 = dy*3 + pair
        int dy = t / 3;
        int pr = t - dy * 3;
        int dx0 = 2 * pr;
        const float* src = (ch < 8) ? sel_filts : green_filts;
        int base = (ch & 7) * 25 + dy * 5 + dx0;
        float v0 = src[base];
        float v1 = (dx0 + 1 < 5) ? src[base + 1] : 0.f;
        filt2[tid] = __builtin_amdgcn_cvt_pkrtz(v0, v1);
    }
    __syncthreads();

    const int b  = blockIdx.z;
    const int y0 = blockIdx.y * 16 + threadIdx.y * 4;       // even
    const int x0 = (blockIdx.x * 64 + threadIdx.x) * 2;     // even
    const float* img = mosaick + (size_t)b * (HH * WW);

    // Window rows y0-2..y0+5, cols x0-2..x0+3 (clamped), packed to half2.
    h2 hE[8][3];    // even-aligned pairs (w0,w1)(w2,w3)(w4,0)  — for odd rows
    h2 hO[8][3];    // odd-aligned  pairs (w1,w2)(w3,w4)(w5,0)  — for even rows
    float cen[4];   // fp32 pass-through values (exact)
    #pragma unroll
    for (int j = 0; j < 8; ++j) {
        int r = y0 + j - 2;
        r = r < 0 ? 0 : (r > HH - 1 ? HH - 1 : r);
        const float* rp = img + (size_t)r * WW;
        float w[6];
        #pragma unroll
        for (int i = 0; i < 6; ++i) {
            int c = x0 + i - 2;
            c = c < 0 ? 0 : (c > WW - 1 ? WW - 1 : c);
            w[i] = rp[c];
        }
        hE[j][0] = __builtin_amdgcn_cvt_pkrtz(w[0], w[1]);
        hE[j][1] = __builtin_amdgcn_cvt_pkrtz(w[2], w[3]);
        hE[j][2] = __builtin_amdgcn_cvt_pkrtz(w[4], 0.f);
        hO[j][0] = __builtin_amdgcn_cvt_pkrtz(w[1], w[2]);
        hO[j][1] = __builtin_amdgcn_cvt_pkrtz(w[3], w[4]);
        hO[j][2] = __builtin_amdgcn_cvt_pkrtz(w[5], 0.f);
        if (j >= 2 && j <= 5)
            cen[j - 2] = ((j - 2) & 1) ? w[3] : w[2];
    }

    // ---- selection bank (ch 0..7) ----
    float accS[4][8];
    #pragma unroll
    for (int p = 0; p < 4; ++p)
        #pragma unroll
        for (int c = 0; c < 8; ++c) accS[p][c] = 0.f;

    #pragma unroll
    for (int dy = 0; dy < 5; ++dy) {
        #pragma unroll
        for (int pr = 0; pr < 3; ++pr) {
            const h2* fp = &filt2[(dy * 3 + pr) * 16];
            h2 f[8];
            #pragma unroll
            for (int c = 0; c < 8; ++c) f[c] = fp[c];
            #pragma unroll
            for (int p = 0; p < 4; ++p) {
                h2 wp = (p & 1) ? hE[p + dy][pr] : hO[p + dy][pr];
                #pragma unroll
                for (int c = 0; c < 8; ++c)
                    accS[p][c] = __builtin_amdgcn_fdot2(wp, f[c], accS[p][c], false);
            }
        }
    }

    // ---- softmax weights (overwrite accS with exp terms) ----
    const float L2E = 1.44269504f;
    float sum[4], gh[4];
    #pragma unroll
    for (int p = 0; p < 4; ++p) {
        float m = accS[p][0];
        #pragma unroll
        for (int c = 1; c < 8; ++c) m = fmaxf(m, accS[p][c]);
        float mL = m * L2E;
        float s = 0.f;
        #pragma unroll
        for (int c = 0; c < 8; ++c) {
            float e = __builtin_amdgcn_exp2f(fmaf(accS[p][c], L2E, -mL));
            accS[p][c] = e;
            s += e;
        }
        sum[p] = s;
        gh[p] = 0.f;
    }

    // ---- green bank (ch 8..15) in two 4-channel halves ----
    #pragma unroll
    for (int hlf = 0; hlf < 2; ++hlf) {
        float accG[4][4];
        #pragma unroll
        for (int p = 0; p < 4; ++p)
            #pragma unroll
            for (int c = 0; c < 4; ++c) accG[p][c] = 0.f;

        #pragma unroll
        for (int dy = 0; dy < 5; ++dy) {
            #pragma unroll
            for (int pr = 0; pr < 3; ++pr) {
                const h2* fp = &filt2[(dy * 3 + pr) * 16 + 8 + 4 * hlf];
                h2 f[4];
                #pragma unroll
                for (int c = 0; c < 4; ++c) f[c] = fp[c];
                #pragma unroll
                for (int p = 0; p < 4; ++p) {
                    h2 wp = (p & 1) ? hE[p + dy][pr] : hO[p + dy][pr];
                    #pragma unroll
                    for (int c = 0; c < 4; ++c)
                        accG[p][c] = __builtin_amdgcn_fdot2(wp, f[c], accG[p][c], false);
                }
            }
        }
        #pragma unroll
        for (int p = 0; p < 4; ++p)
            #pragma unroll
            for (int c = 0; c < 4; ++c)
                gh[p] = fmaf(accS[p][4 * hlf + c], accG[p][c], gh[p]);
    }

    // ---- epilogue ----
    float* outp = out + (size_t)b * (HH * WW);
    #pragma unroll
    for (int p = 0; p < 4; ++p) {
        float g = gh[p] * __builtin_amdgcn_rcpf(sum[p]);
        float2 o;
        if ((p & 1) == 0) { o.x = cen[p]; o.y = g; }       // green at x0
        else              { o.x = g;      o.y = cen[p]; }  // green at x0+1
        *(float2*)(outp + (size_t)(y0 + p) * WW + x0) = o;
    }
}

extern "C" void kernel_launch(void* const* d_in, const int* in_sizes, int n_in,
                              void* d_out, int out_size, void* d_ws, size_t ws_size,
                              hipStream_t stream) {
    const float* mosaick     = (const float*)d_in[0];
    const float* sel_filts   = (const float*)d_in[1];
    const float* green_filts = (const float*)d_in[2];
    float* out = (float*)d_out;
    const int HW = HH * WW;
    const int B = in_sizes[0] / HW;          // 8
    dim3 grid(WW / 128, HH / 16, B);         // (8, 64, 8) = 4096 blocks
    dim3 block(64, 4, 1);
    hipLaunchKernelGGL(demosaick_kernel, grid, block, 0, stream,
                       mosaick, sel_filts, green_filts, out);
}